// Round 1
// baseline (449.120 us; speedup 1.0000x reference)
//
#include <hip/hip_runtime.h>
#include <cstdint>

#define EPS 1e-6f

constexpr int Bsz = 4, Hn = 16, Lseq = 8192, Dd = 64;
constexpr int BH = Bsz * Hn;              // 64
constexpr int CHUNK = 128;                // rows per wave-chunk
constexpr int CPB = Lseq / CHUNK;         // 64 chunks per (b,h)
constexpr int NCHUNKS = BH * CPB;         // 4096
constexpr int WPB = 4;                    // waves per block
constexpr int R = 4;                      // rows per row-group per sub-chunk
constexpr int SUB = 4 * R;                // 16 rows per sub-chunk

// feature map: x>0 ? x+1 : exp(x). __expf -> v_exp_f32 (cheap, ~1 ULP)
__device__ __forceinline__ float phi(float x) {
    return x > 0.0f ? x + 1.0f : __expf(x);
}

// ---------------- kernel 1: per-chunk aggregates (order-free) ----------------
// Memory-bound streaming (268 MB); unchanged from the 449.7 µs version.
__global__ __launch_bounds__(256) void partials_kernel(
    const float* __restrict__ k, const float* __restrict__ v,
    const float* __restrict__ mask,
    float* __restrict__ pk, float* __restrict__ pkv)
{
    const int wave = blockIdx.x * WPB + (threadIdx.x >> 6);
    const int lane = threadIdx.x & 63;
    const int rg = lane >> 4;          // row group 0..3
    const int dg = lane & 15;          // dim group: dims [4*dg, 4*dg+4)
    const int bh = wave / CPB;
    const int c  = wave % CPB;
    const int b  = bh / Hn;
    const int l0 = c * CHUNK;

    float4 ak  = make_float4(0.f, 0.f, 0.f, 0.f);
    float4 akv = make_float4(0.f, 0.f, 0.f, 0.f);

    for (int i = 0; i < CHUNK; i += 4) {
        const int l = l0 + i + rg;
        const size_t off = ((size_t)bh * Lseq + l) * Dd + dg * 4;
        const float4 k4 = *(const float4*)(k + off);
        const float4 v4 = *(const float4*)(v + off);
        const float m = mask[(size_t)b * Lseq + l];
        float t;
        t = phi(k4.x) * m; ak.x += t; akv.x += t * (v4.x * m);
        t = phi(k4.y) * m; ak.y += t; akv.y += t * (v4.y * m);
        t = phi(k4.z) * m; ak.z += t; akv.z += t * (v4.z * m);
        t = phi(k4.w) * m; ak.w += t; akv.w += t * (v4.w * m);
    }

    // reduce across the 4 row groups (xor 16, 32) — butterfly: all lanes get total
    #pragma unroll
    for (int off = 16; off <= 32; off <<= 1) {
        ak.x  += __shfl_xor(ak.x,  off, 64);
        ak.y  += __shfl_xor(ak.y,  off, 64);
        ak.z  += __shfl_xor(ak.z,  off, 64);
        ak.w  += __shfl_xor(ak.w,  off, 64);
        akv.x += __shfl_xor(akv.x, off, 64);
        akv.y += __shfl_xor(akv.y, off, 64);
        akv.z += __shfl_xor(akv.z, off, 64);
        akv.w += __shfl_xor(akv.w, off, 64);
    }

    if (rg == 0) {
        const size_t o = (size_t)wave * Dd + dg * 4;
        *(float4*)(pk  + o) = ak;
        *(float4*)(pkv + o) = akv;
    }
}

// ------------- kernel 2: exclusive scan over chunk aggregates ----------------
// v2: parallel — one wave per (bh, d), lane = chunk index, 6-step shfl scan.
// Replaces the 64-wave serial loop (was a ~20 µs latency chain at 0.25% occupancy).
__global__ __launch_bounds__(256) void scan_kernel(
    float* __restrict__ pk, float* __restrict__ pkv)
{
    const int w    = blockIdx.x * 4 + (threadIdx.x >> 6);  // 0..4095
    const int lane = threadIdx.x & 63;                     // chunk index c
    const int bh   = w >> 6;                               // /64
    const int d    = w & 63;
    const size_t o = ((size_t)(bh * CPB + lane)) * Dd + d;
    const float tk  = pk[o];
    const float tkv = pkv[o];
    float ik = tk, ikv = tkv;
    #pragma unroll
    for (int off = 1; off <= 32; off <<= 1) {
        const float t1 = __shfl_up(ik,  off, 64);
        const float t2 = __shfl_up(ikv, off, 64);
        if (lane >= off) { ik += t1; ikv += t2; }
    }
    pk[o]  = ik  - tk;    // exclusive prefix
    pkv[o] = ikv - tkv;
}

// ---------------- kernel 3: final pass with exact inclusive prefix -----------
// v2: blocked intra-chunk scan. Each rg owns R=4 consecutive rows; local
// inclusive prefixes accumulate sequentially in registers (statically indexed
// after full unroll), and the cross-rg shfl scan runs once per 16-row
// sub-chunk on block totals. Cross-lane ops: 11/row -> 2.5/row.
__global__ __launch_bounds__(256) void final_kernel(
    const float* __restrict__ q, const float* __restrict__ k,
    const float* __restrict__ v, const float* __restrict__ mask,
    const float* __restrict__ pk, const float* __restrict__ pkv,
    float* __restrict__ out)
{
    const int wave = blockIdx.x * WPB + (threadIdx.x >> 6);
    const int lane = threadIdx.x & 63;
    const int rg = lane >> 4;
    const int dg = lane & 15;
    const int bh = wave / CPB;
    const int c  = wave % CPB;
    const int b  = bh / Hn;
    const int l0 = c * CHUNK;

    const size_t po = (size_t)wave * Dd + dg * 4;
    float4 Sk  = *(const float4*)(pk  + po);   // exclusive prefix for this chunk
    float4 Skv = *(const float4*)(pkv + po);

    for (int s = 0; s < CHUNK / SUB; ++s) {
        const int lbase = l0 + s * SUB + rg * R;  // blocked row assignment

        float4 pa[R], pakv[R];
        float  ms[R];
        float4 ra   = make_float4(0.f, 0.f, 0.f, 0.f);
        float4 rakv = make_float4(0.f, 0.f, 0.f, 0.f);

        // Loop A: sequential local inclusive prefix over this rg's R rows
        #pragma unroll
        for (int j = 0; j < R; ++j) {
            const int l = lbase + j;
            const size_t off = ((size_t)bh * Lseq + l) * Dd + dg * 4;
            const float4 k4 = *(const float4*)(k + off);
            const float4 v4 = *(const float4*)(v + off);
            const float m = mask[(size_t)b * Lseq + l];
            ms[j] = m;
            float t;
            t = phi(k4.x) * m; ra.x += t; rakv.x += t * (v4.x * m);
            t = phi(k4.y) * m; ra.y += t; rakv.y += t * (v4.y * m);
            t = phi(k4.z) * m; ra.z += t; rakv.z += t * (v4.z * m);
            t = phi(k4.w) * m; ra.w += t; rakv.w += t * (v4.w * m);
            pa[j]   = ra;
            pakv[j] = rakv;
        }

        // Inclusive scan of sub-block totals across the 4 row groups
        float4 ia = ra, iakv = rakv;
        float t;
        t = __shfl_up(ia.x,   16, 64); if (rg >= 1) ia.x   += t;
        t = __shfl_up(ia.y,   16, 64); if (rg >= 1) ia.y   += t;
        t = __shfl_up(ia.z,   16, 64); if (rg >= 1) ia.z   += t;
        t = __shfl_up(ia.w,   16, 64); if (rg >= 1) ia.w   += t;
        t = __shfl_up(iakv.x, 16, 64); if (rg >= 1) iakv.x += t;
        t = __shfl_up(iakv.y, 16, 64); if (rg >= 1) iakv.y += t;
        t = __shfl_up(iakv.z, 16, 64); if (rg >= 1) iakv.z += t;
        t = __shfl_up(iakv.w, 16, 64); if (rg >= 1) iakv.w += t;
        t = __shfl_up(ia.x,   32, 64); if (rg >= 2) ia.x   += t;
        t = __shfl_up(ia.y,   32, 64); if (rg >= 2) ia.y   += t;
        t = __shfl_up(ia.z,   32, 64); if (rg >= 2) ia.z   += t;
        t = __shfl_up(ia.w,   32, 64); if (rg >= 2) ia.w   += t;
        t = __shfl_up(iakv.x, 32, 64); if (rg >= 2) iakv.x += t;
        t = __shfl_up(iakv.y, 32, 64); if (rg >= 2) iakv.y += t;
        t = __shfl_up(iakv.z, 32, 64); if (rg >= 2) iakv.z += t;
        t = __shfl_up(iakv.w, 32, 64); if (rg >= 2) iakv.w += t;

        // exclusive offset for this rg = chunk prefix + (inclusive - own total)
        const float4 ofk = make_float4(Sk.x + ia.x - ra.x, Sk.y + ia.y - ra.y,
                                       Sk.z + ia.z - ra.z, Sk.w + ia.w - ra.w);
        const float4 ofkv = make_float4(Skv.x + iakv.x - rakv.x, Skv.y + iakv.y - rakv.y,
                                        Skv.z + iakv.z - rakv.z, Skv.w + iakv.w - rakv.w);

        // advance chunk prefix by the whole sub-chunk total (inclusive at rg==3)
        Sk.x  += __shfl(ia.x,   48 + dg, 64);
        Sk.y  += __shfl(ia.y,   48 + dg, 64);
        Sk.z  += __shfl(ia.z,   48 + dg, 64);
        Sk.w  += __shfl(ia.w,   48 + dg, 64);
        Skv.x += __shfl(iakv.x, 48 + dg, 64);
        Skv.y += __shfl(iakv.y, 48 + dg, 64);
        Skv.z += __shfl(iakv.z, 48 + dg, 64);
        Skv.w += __shfl(iakv.w, 48 + dg, 64);

        // Loop B: read q, produce output for this rg's R rows
        #pragma unroll
        for (int j = 0; j < R; ++j) {
            const int l = lbase + j;
            const size_t off = ((size_t)bh * Lseq + l) * Dd + dg * 4;
            const float4 q4 = *(const float4*)(q + off);
            const float m = ms[j];

            float4 fq;
            fq.x = phi(q4.x); fq.y = phi(q4.y); fq.z = phi(q4.z); fq.w = phi(q4.w);

            const float4 ik  = make_float4(ofk.x  + pa[j].x,   ofk.y  + pa[j].y,
                                           ofk.z  + pa[j].z,   ofk.w  + pa[j].w);
            const float4 ikv = make_float4(ofkv.x + pakv[j].x, ofkv.y + pakv[j].y,
                                           ofkv.z + pakv[j].z, ofkv.w + pakv[j].w);

            // z = (sum_d phi(q)*k_cumsum + EPS) * mask  (reduce over 16 dg lanes)
            float p = fq.x * ik.x + fq.y * ik.y + fq.z * ik.z + fq.w * ik.w;
            p += __shfl_xor(p, 1, 64);
            p += __shfl_xor(p, 2, 64);
            p += __shfl_xor(p, 4, 64);
            p += __shfl_xor(p, 8, 64);
            const float z = (p + EPS) * m;
            const float inv = 1.0f / z;

            float4 o4;
            o4.x = fq.x * ikv.x * inv;
            o4.y = fq.y * ikv.y * inv;
            o4.z = fq.z * ikv.z * inv;
            o4.w = fq.w * ikv.w * inv;
            *(float4*)(out + off) = o4;
        }
    }
}

extern "C" void kernel_launch(void* const* d_in, const int* in_sizes, int n_in,
                              void* d_out, int out_size, void* d_ws, size_t ws_size,
                              hipStream_t stream) {
    const float* q    = (const float*)d_in[0];
    const float* k    = (const float*)d_in[1];
    const float* v    = (const float*)d_in[2];
    const float* mask = (const float*)d_in[3];
    float* out = (float*)d_out;

    // workspace: 2 arrays of NCHUNKS*64 floats = 2 MiB total
    float* pk  = (float*)d_ws;
    float* pkv = pk + (size_t)NCHUNKS * Dd;

    partials_kernel<<<NCHUNKS / WPB, 256, 0, stream>>>(k, v, mask, pk, pkv);
    scan_kernel<<<(BH * Dd) / 4, 256, 0, stream>>>(pk, pkv);
    final_kernel<<<NCHUNKS / WPB, 256, 0, stream>>>(q, k, v, mask, pk, pkv, out);
}